// Round 10
// baseline (960.949 us; speedup 1.0000x reference)
//
#include <hip/hip_runtime.h>
#include <hip/hip_cooperative_groups.h>

namespace cg = cooperative_groups;

#define NN 100000
#define NE 1200000
#define DD 64
#define NBUCK 196        // ceil(NN/512) coarse buckets (dst >> 9)
#define BCAP 7168        // bucket capacity: mean 6122, +13 sigma
#define TILE 8192        // edges per binning block
#define NB1 147          // ceil(NE/TILE)
#define NB_G 1563        // ceil(NN/64) gemm tiles
#define GRID 1024        // 4 blocks/CU co-resident (cooperative)
#define FIX25 33554432.0f
#define FIX25_INV (1.0f/33554432.0f)

typedef short bf16x8 __attribute__((ext_vector_type(8)));
typedef float f32x4  __attribute__((ext_vector_type(4)));

static __device__ __forceinline__ unsigned short f2bf(float f) {
    unsigned int u = __float_as_uint(f);
    unsigned int r = (u + 0x7fffu + ((u >> 16) & 1u)) >> 16;   // RNE
    return (unsigned short)r;
}
static __device__ __forceinline__ float bf2f(unsigned short s) {
    return __uint_as_float(((unsigned int)s) << 16);
}

// ============= GEMM tile body: h16[r0:r0+64] = bf16(x @ W) =============
// 256 threads = 4 waves; wave computes 16 rows x 64 cols via 16x16x32 MFMA.

static __device__ __forceinline__ void gemm_body(
    const float* __restrict__ x, const float* __restrict__ W,
    unsigned short* __restrict__ h16, int r0, int t,
    unsigned short* Xs, unsigned short* Ws)
{
    {   // stage W[k][col] -> Ws[col][k] bf16 (transpose), pad 72; W is L2-hot
        int col = t >> 2, k0 = (t & 3) * 16;
        #pragma unroll
        for (int i = 0; i < 16; ++i)
            Ws[col * 72 + k0 + i] = f2bf(W[(k0 + i) * 64 + col]);
    }
    {   // stage X: fp32 -> bf16, 16 floats/thread
        int row = t >> 2, seg = (t & 3) * 16;
        int gr = r0 + row;
        float4 v0 = {0,0,0,0}, v1 = v0, v2 = v0, v3 = v0;
        if (gr < NN) {
            const float4* p = (const float4*)(x + (size_t)gr * DD + seg);
            v0 = p[0]; v1 = p[1]; v2 = p[2]; v3 = p[3];
        }
        ushort4 h0 = { f2bf(v0.x), f2bf(v0.y), f2bf(v0.z), f2bf(v0.w) };
        ushort4 h1 = { f2bf(v1.x), f2bf(v1.y), f2bf(v1.z), f2bf(v1.w) };
        ushort4 h2 = { f2bf(v2.x), f2bf(v2.y), f2bf(v2.z), f2bf(v2.w) };
        ushort4 h3 = { f2bf(v3.x), f2bf(v3.y), f2bf(v3.z), f2bf(v3.w) };
        *(ushort4*)&Xs[row * 72 + seg]      = h0;
        *(ushort4*)&Xs[row * 72 + seg + 4]  = h1;
        *(ushort4*)&Xs[row * 72 + seg + 8]  = h2;
        *(ushort4*)&Xs[row * 72 + seg + 12] = h3;
    }
    __syncthreads();

    const int wv = t >> 6;
    const int ln = t & 63;
    const int m  = ln & 15;
    const int q  = ln >> 4;
    const int arow = wv * 16 + m;

    bf16x8 a0 = *(const bf16x8*)&Xs[arow * 72 + q * 8];
    bf16x8 a1 = *(const bf16x8*)&Xs[arow * 72 + 32 + q * 8];

    f32x4 acc[4];
    #pragma unroll
    for (int c = 0; c < 4; ++c) {
        bf16x8 b0 = *(const bf16x8*)&Ws[(c * 16 + m) * 72 + q * 8];
        bf16x8 b1 = *(const bf16x8*)&Ws[(c * 16 + m) * 72 + 32 + q * 8];
        f32x4 z = {0.f, 0.f, 0.f, 0.f};
        z = __builtin_amdgcn_mfma_f32_16x16x32_bf16(a0, b0, z, 0, 0, 0);
        z = __builtin_amdgcn_mfma_f32_16x16x32_bf16(a1, b1, z, 0, 0, 0);
        acc[c] = z;
    }

    #pragma unroll
    for (int r = 0; r < 4; ++r) {
        int grow = r0 + wv * 16 + q * 4 + r;
        if (grow < NN) {
            #pragma unroll
            for (int c = 0; c < 4; ++c)
                h16[(size_t)grow * DD + c * 16 + m] = f2bf(acc[c][r]);
        }
    }
}

// ============= gather phase (R8-proven body): one wave per node =============
// csr entry: [src:17 | bf15(dis[src]*ew):15]; acc = bias + di^2*h[n] +
// sum_e (norm_e * di) * h[src_e].

template <bool FINAL>
static __device__ __forceinline__ void gather_phase(
    const unsigned short* __restrict__ h16, const float* __restrict__ bias,
    const float* __restrict__ dis, const unsigned int* __restrict__ rowdeg,
    const unsigned int* __restrict__ csr,
    const float* __restrict__ prev, float* __restrict__ out)
{
    const int wv   = threadIdx.x >> 6;
    const int lane = threadIdx.x & 63;

    for (int g = blockIdx.x; g < NN / 4; g += GRID) {
        const int node = __builtin_amdgcn_readfirstlane(g * 4 + wv);

        const unsigned int rd = rowdeg[node];
        const int deg = rd & 63;
        const float di = dis[node];

        float a0 = fmaf(di * di, bf2f(h16[(size_t)node * DD + lane]), bias[lane]);
        float a1 = 0.f, a2 = 0.f, a3 = 0.f;

        const unsigned int* seg = csr + (rd >> 6);
        int j = 0;
        for (; j + 3 < deg; j += 4) {
            unsigned int e0 = seg[j],     e1 = seg[j + 1];
            unsigned int e2 = seg[j + 2], e3 = seg[j + 3];
            float n0 = bf2f((unsigned short)(e0 & 0x7fffu)) * di;
            float n1 = bf2f((unsigned short)(e1 & 0x7fffu)) * di;
            float n2 = bf2f((unsigned short)(e2 & 0x7fffu)) * di;
            float n3 = bf2f((unsigned short)(e3 & 0x7fffu)) * di;
            a0 = fmaf(n0, bf2f(h16[(size_t)(e0 >> 15) * DD + lane]), a0);
            a1 = fmaf(n1, bf2f(h16[(size_t)(e1 >> 15) * DD + lane]), a1);
            a2 = fmaf(n2, bf2f(h16[(size_t)(e2 >> 15) * DD + lane]), a2);
            a3 = fmaf(n3, bf2f(h16[(size_t)(e3 >> 15) * DD + lane]), a3);
        }
        for (; j < deg; ++j) {
            unsigned int e = seg[j];
            a0 = fmaf(bf2f((unsigned short)(e & 0x7fffu)) * di,
                      bf2f(h16[(size_t)(e >> 15) * DD + lane]), a0);
        }

        float v = fmaxf((a0 + a1) + (a2 + a3), 0.f);
        int idx = node * DD + lane;
        if (FINAL) out[idx] = 0.5f * (prev[idx] + v);
        else       out[idx] = v;
    }
}

// ============= the mega kernel: whole pipeline, one launch =============

__global__ __launch_bounds__(256, 4) void mega(
    const int* __restrict__ src, const int* __restrict__ dst,
    const float* __restrict__ ew,
    const float* __restrict__ x, const float* __restrict__ W1,
    const float* __restrict__ b1, const float* __restrict__ W2,
    const float* __restrict__ b2, float* __restrict__ out,
    int* __restrict__ cursor, unsigned long long* __restrict__ stage,
    unsigned int* __restrict__ csr, unsigned int* __restrict__ rowdeg,
    float* __restrict__ dis, unsigned short* __restrict__ h16)
{
    cg::grid_group grid = cg::this_grid();

    __shared__ unsigned short Xs[64 * 72];       // 9216 B  (gemm)
    __shared__ unsigned short Ws[64 * 72];       // 9216 B  (gemm)
    __shared__ int      scnt[512];               // 2048 B  (bin cnt / bucket cnt)
    __shared__ unsigned ssum[512];               // 2048 B  (bucket ew sums)
    __shared__ int      sps[256];                // 1024 B  (pair scan)
    __shared__ int      sresv[NBUCK];            //  784 B  (bin reservations)

    const int t   = threadIdx.x;
    const int blk = blockIdx.x;

    // ---- P0: zero bucket cursors ----
    if (blk == 0 && t < NBUCK) cursor[t] = 0;
    grid.sync();

    // ---- P1: coarse binning (blocks < NB1) + layer-1 GEMM (rest) ----
    if (blk < NB1) {
        const int base = blk * TILE;
        if (t < NBUCK) scnt[t] = 0;
        __syncthreads();
        #pragma unroll 8
        for (int k = 0; k < TILE / 256; ++k) {
            int e = base + k * 256 + t;
            if (e < NE) atomicAdd(&scnt[dst[e] >> 9], 1);
        }
        __syncthreads();
        if (t < NBUCK) {
            int c = scnt[t];
            sresv[t] = c ? atomicAdd(&cursor[t], c) : 0;
            scnt[t] = 0;
        }
        __syncthreads();
        #pragma unroll 8
        for (int k = 0; k < TILE / 256; ++k) {
            int e = base + k * 256 + t;
            if (e < NE) {
                int d = dst[e];
                int b = d >> 9;
                int r = atomicAdd(&scnt[b], 1);
                int pos = sresv[b] + r;
                if (pos < BCAP) {
                    unsigned int meta = ((unsigned int)(d & 511) << 17) |
                                        (unsigned int)src[e];
                    stage[(size_t)b * BCAP + pos] =
                        ((unsigned long long)meta << 32) | __float_as_uint(ew[e]);
                }
            }
        }
    } else {
        for (int tile = blk - NB1; tile < NB_G; tile += GRID - NB1) {
            gemm_body(x, W1, h16, tile * 64, t, Xs, Ws);
            __syncthreads();
        }
    }
    grid.sync();

    // ---- P2: per-bucket count/sum -> scan -> dis + rowdeg ----
    if (blk < NBUCK) {
        const int b  = blk;
        const int n0 = b << 9;
        const int cntb = min(cursor[b], BCAP);

        scnt[t] = 0; scnt[t + 256] = 0;
        ssum[t] = 0; ssum[t + 256] = 0;
        __syncthreads();
        for (int k = t; k < cntb; k += 256) {
            unsigned long long E = stage[(size_t)b * BCAP + k];
            int dl = (int)(E >> 49);
            float w = __uint_as_float((unsigned int)E);
            atomicAdd(&scnt[dl], 1);
            atomicAdd(&ssum[dl], (unsigned)(w * FIX25));
        }
        __syncthreads();
        int a0 = scnt[2 * t], a1 = scnt[2 * t + 1];
        sps[t] = a0 + a1;
        __syncthreads();
        for (int off = 1; off < 256; off <<= 1) {
            int add = (t >= off) ? sps[t - off] : 0;
            __syncthreads();
            sps[t] += add;
            __syncthreads();
        }
        int eb = sps[t] - (a0 + a1);        // exclusive base of node 2t
        int node0 = n0 + 2 * t;
        if (node0 < NN) {
            dis[node0] = rsqrtf(1.0f + (float)ssum[2 * t] * FIX25_INV);
            rowdeg[node0] = ((unsigned)(b * BCAP + eb) << 6) | (unsigned)min(a0, 63);
        }
        if (node0 + 1 < NN) {
            dis[node0 + 1] = rsqrtf(1.0f + (float)ssum[2 * t + 1] * FIX25_INV);
            rowdeg[node0 + 1] =
                ((unsigned)(b * BCAP + eb + a0) << 6) | (unsigned)min(a1, 63);
        }
    }
    grid.sync();

    // ---- P3: per-bucket baked CSR write (needs global dis) ----
    if (blk < NBUCK) {
        const int b  = blk;
        const int n0 = b << 9;
        const int cntb = min(cursor[b], BCAP);

        scnt[t] = 0; scnt[t + 256] = 0;
        __syncthreads();
        for (int k = t; k < cntb; k += 256) {
            unsigned long long E = stage[(size_t)b * BCAP + k];
            unsigned int meta = (unsigned int)(E >> 32);
            int dl = meta >> 17;
            unsigned int s = meta & 0x1ffffu;
            float w = __uint_as_float((unsigned int)E);
            int r = atomicAdd(&scnt[dl], 1);
            if (r < 63) {
                unsigned int base = rowdeg[n0 + dl] >> 6;
                csr[base + r] = (s << 15) | (f2bf(dis[s] * w) & 0x7fffu);
            }
        }
    }
    grid.sync();

    // ---- P4: layer-1 gather ----
    gather_phase<false>(h16, b1, dis, rowdeg, csr, out, out);
    grid.sync();

    // ---- P5: layer-2 GEMM (input = x1 in out) ----
    for (int tile = blk; tile < NB_G; tile += GRID) {
        gemm_body(out, W2, h16, tile * 64, t, Xs, Ws);
        __syncthreads();
    }
    grid.sync();

    // ---- P6: layer-2 gather + final combine ----
    gather_phase<true>(h16, b2, dis, rowdeg, csr, out, out);
}

// ============= launch =============

extern "C" void kernel_launch(void* const* d_in, const int* in_sizes, int n_in,
                              void* d_out, int out_size, void* d_ws, size_t ws_size,
                              hipStream_t stream) {
    const float* x   = (const float*)d_in[0];
    const int*   ei  = (const int*)d_in[1];
    const float* ewt = (const float*)d_in[2];
    const float* W1  = (const float*)d_in[3];
    const float* b1  = (const float*)d_in[4];
    const float* W2  = (const float*)d_in[5];
    const float* b2  = (const float*)d_in[6];
    float* out = (float*)d_out;

    const int* srcv = ei;
    const int* dstv = ei + NE;

    // workspace layout, 4B slots (d_ws 16B aligned); ~30.5 MB total
    float* wsf = (float*)d_ws;
    int* cursor = (int*)wsf;                                         // @0 (256)
    float* dis = wsf + 256;                                          // 100000 -> pad @100352
    unsigned int* rowdeg = (unsigned int*)(wsf + 100352);            // 100000 -> pad @200448
    unsigned long long* stage = (unsigned long long*)(wsf + 200448); // NBUCK*BCAP u64
    unsigned int* csr = (unsigned int*)(wsf + 200448 + 2 * NBUCK * BCAP);
    unsigned short* h16 = (unsigned short*)(csr + NBUCK * BCAP);     // NN*64 bf16

    void* args[] = {
        (void*)&srcv, (void*)&dstv, (void*)&ewt,
        (void*)&x, (void*)&W1, (void*)&b1, (void*)&W2, (void*)&b2, (void*)&out,
        (void*)&cursor, (void*)&stage, (void*)&csr, (void*)&rowdeg,
        (void*)&dis, (void*)&h16
    };
    hipLaunchCooperativeKernel((void*)mega, dim3(GRID), dim3(256),
                               args, 0, stream);
}

// Round 11
// 239.425 us; speedup vs baseline: 4.0136x; 4.0136x over previous
//
#include <hip/hip_runtime.h>

#define NN 100000
#define NE 1200000
#define DD 64
#define NBUCK 196        // ceil(NN/512) coarse buckets (dst >> 9)
#define BCAP 7168        // bucket capacity: mean 6122, +13 sigma
#define TILE 8192        // edges per pass-1 binning block
#define NB1 147          // ceil(NE/TILE)
#define NB_G 1563        // ceil(NN/64) gemm blocks
#define FIX25 33554432.0f
#define FIX25_INV (1.0f/33554432.0f)

typedef short bf16x8 __attribute__((ext_vector_type(8)));
typedef float f32x4  __attribute__((ext_vector_type(4)));

static __device__ __forceinline__ unsigned short f2bf(float f) {
    unsigned int u = __float_as_uint(f);
    unsigned int r = (u + 0x7fffu + ((u >> 16) & 1u)) >> 16;   // RNE
    return (unsigned short)r;
}
static __device__ __forceinline__ float bf2f(unsigned short s) {
    return __uint_as_float(((unsigned int)s) << 16);
}

// ============= shared GEMM body: h16 = bf16(x @ W), W fp32 row-major =============
// 256 threads = 4 waves; 64-row tile; wave computes 16 rows x 64 cols.

static __device__ __forceinline__ void gemm_body(
    const float* __restrict__ x, const float* __restrict__ W,
    unsigned short* __restrict__ h16, int r0, int t,
    unsigned short* Xs, unsigned short* Ws)
{
    {   // stage W[k][col] -> Ws[col][k] bf16 (transpose), pad 72; W is L2-hot
        int col = t >> 2, k0 = (t & 3) * 16;
        #pragma unroll
        for (int i = 0; i < 16; ++i)
            Ws[col * 72 + k0 + i] = f2bf(W[(k0 + i) * 64 + col]);
    }
    {   // stage X: fp32 -> bf16, 16 floats/thread
        int row = t >> 2, seg = (t & 3) * 16;
        int gr = r0 + row;
        float4 v0 = {0,0,0,0}, v1 = v0, v2 = v0, v3 = v0;
        if (gr < NN) {
            const float4* p = (const float4*)(x + (size_t)gr * DD + seg);
            v0 = p[0]; v1 = p[1]; v2 = p[2]; v3 = p[3];
        }
        ushort4 h0 = { f2bf(v0.x), f2bf(v0.y), f2bf(v0.z), f2bf(v0.w) };
        ushort4 h1 = { f2bf(v1.x), f2bf(v1.y), f2bf(v1.z), f2bf(v1.w) };
        ushort4 h2 = { f2bf(v2.x), f2bf(v2.y), f2bf(v2.z), f2bf(v2.w) };
        ushort4 h3 = { f2bf(v3.x), f2bf(v3.y), f2bf(v3.z), f2bf(v3.w) };
        *(ushort4*)&Xs[row * 72 + seg]      = h0;
        *(ushort4*)&Xs[row * 72 + seg + 4]  = h1;
        *(ushort4*)&Xs[row * 72 + seg + 8]  = h2;
        *(ushort4*)&Xs[row * 72 + seg + 12] = h3;
    }
    __syncthreads();

    const int wv = t >> 6;
    const int ln = t & 63;
    const int m  = ln & 15;
    const int q  = ln >> 4;
    const int arow = wv * 16 + m;

    bf16x8 a0 = *(const bf16x8*)&Xs[arow * 72 + q * 8];
    bf16x8 a1 = *(const bf16x8*)&Xs[arow * 72 + 32 + q * 8];

    f32x4 acc[4];
    #pragma unroll
    for (int c = 0; c < 4; ++c) {
        bf16x8 b0 = *(const bf16x8*)&Ws[(c * 16 + m) * 72 + q * 8];
        bf16x8 b1 = *(const bf16x8*)&Ws[(c * 16 + m) * 72 + 32 + q * 8];
        f32x4 z = {0.f, 0.f, 0.f, 0.f};
        z = __builtin_amdgcn_mfma_f32_16x16x32_bf16(a0, b0, z, 0, 0, 0);
        z = __builtin_amdgcn_mfma_f32_16x16x32_bf16(a1, b1, z, 0, 0, 0);
        acc[c] = z;
    }

    #pragma unroll
    for (int r = 0; r < 4; ++r) {
        int grow = r0 + wv * 16 + q * 4 + r;
        if (grow < NN) {
            #pragma unroll
            for (int c = 0; c < 4; ++c)
                h16[(size_t)grow * DD + c * 16 + m] = f2bf(acc[c][r]);
        }
    }
}

// ============= pass 1: coarse binning (2-sweep, LDS counts) + gemm1 fused =====
// Blocks [0,NB1): bin TILE edges; stage u64: [dl:9|src:17]:32 high, fp32 ew low.
// Blocks [NB1,...): layer-1 GEMM (independent; co-scheduled under binning).

__global__ __launch_bounds__(256) void pass1_gemm(
    const int* __restrict__ src, const int* __restrict__ dst,
    const float* __restrict__ ew, int* __restrict__ cursor,
    unsigned long long* __restrict__ stage,
    const float* __restrict__ x, const float* __restrict__ W1,
    unsigned short* __restrict__ h16)
{
    __shared__ unsigned short Xs[64 * 72];
    __shared__ unsigned short Ws[64 * 72];
    __shared__ int cnt[NBUCK];
    __shared__ int resv[NBUCK];

    const int t = threadIdx.x;

    if (blockIdx.x >= NB1) {
        gemm_body(x, W1, h16, (blockIdx.x - NB1) * 64, t, Xs, Ws);
        return;
    }

    const int base = blockIdx.x * TILE;
    if (t < NBUCK) cnt[t] = 0;
    __syncthreads();

    #pragma unroll 8
    for (int k = 0; k < TILE / 256; ++k) {
        int e = base + k * 256 + t;
        if (e < NE) atomicAdd(&cnt[dst[e] >> 9], 1);
    }
    __syncthreads();
    if (t < NBUCK) {
        int c = cnt[t];
        resv[t] = c ? atomicAdd(&cursor[t], c) : 0;
        cnt[t] = 0;
    }
    __syncthreads();
    #pragma unroll 8
    for (int k = 0; k < TILE / 256; ++k) {
        int e = base + k * 256 + t;
        if (e < NE) {
            int d = dst[e];
            int b = d >> 9;
            int r = atomicAdd(&cnt[b], 1);
            int pos = resv[b] + r;
            if (pos < BCAP) {
                unsigned int meta = ((unsigned int)(d & 511) << 17) |
                                    (unsigned int)src[e];
                stage[(size_t)b * BCAP + pos] =
                    ((unsigned long long)meta << 32) | __float_as_uint(ew[e]);
            }
        }
    }
}

// ============= pass 2a: per-bucket count/sum -> scan -> dis + rowdeg =========
// One block (512 thr) per bucket. rowdeg = (abs_csr_base << 6) | deg.

__global__ __launch_bounds__(512) void pass2a(
    const unsigned long long* __restrict__ stage, const int* __restrict__ cursor,
    unsigned int* __restrict__ rowdeg, float* __restrict__ dis)
{
    __shared__ int cnt[512];
    __shared__ unsigned sum[512];
    __shared__ int scn[512];

    const int b = blockIdx.x;
    const int t = threadIdx.x;
    const int n0 = b << 9;
    const int cntb = min(cursor[b], BCAP);

    cnt[t] = 0; sum[t] = 0;
    __syncthreads();

    for (int k = t; k < cntb; k += 512) {
        unsigned long long E = stage[(size_t)b * BCAP + k];
        int dl = (int)(E >> 49);                      // meta>>17
        float w = __uint_as_float((unsigned int)E);
        atomicAdd(&cnt[dl], 1);
        atomicAdd(&sum[dl], (unsigned)(w * FIX25));
    }
    __syncthreads();

    int v = cnt[t];
    scn[t] = v;
    __syncthreads();
    for (int off = 1; off < 512; off <<= 1) {
        int add = (t >= off) ? scn[t - off] : 0;
        __syncthreads();
        scn[t] += add;
        __syncthreads();
    }

    int node = n0 + t;
    if (node < NN) {
        dis[node] = rsqrtf(1.0f + (float)sum[t] * FIX25_INV);
        rowdeg[node] = ((unsigned)(b * BCAP + scn[t] - v) << 6) |
                       (unsigned)min(v, 63);
    }
}

// ============= pass 2b: rank replay -> baked CSR write =======================
// csr entry: [src:17 | bf15(dis[src]*ew):15]. rowdeg bases cached in LDS.

__global__ __launch_bounds__(512) void pass2b(
    const unsigned long long* __restrict__ stage, const int* __restrict__ cursor,
    const unsigned int* __restrict__ rowdeg, const float* __restrict__ dis,
    unsigned int* __restrict__ csr)
{
    __shared__ int cnt[512];
    __shared__ unsigned sbase[512];

    const int b = blockIdx.x;
    const int t = threadIdx.x;
    const int n0 = b << 9;
    const int cntb = min(cursor[b], BCAP);

    cnt[t] = 0;
    sbase[t] = (n0 + t < NN) ? (rowdeg[n0 + t] >> 6) : 0u;
    __syncthreads();

    for (int k = t; k < cntb; k += 512) {
        unsigned long long E = stage[(size_t)b * BCAP + k];
        unsigned int meta = (unsigned int)(E >> 32);
        int dl = meta >> 17;
        unsigned int s = meta & 0x1ffffu;
        float w = __uint_as_float((unsigned int)E);
        int r = atomicAdd(&cnt[dl], 1);
        if (r < 63)
            csr[sbase[dl] + r] = (s << 15) | (f2bf(dis[s] * w) & 0x7fffu);
    }
}

// ============= gather (R8-proven body + non-temporal streaming) ==============
// one wave per node; acc = bias + di^2*h[n] + sum_e (norm_e * di) * h[src_e]

template <bool FINAL>
__global__ __launch_bounds__(256) void gather(
    const unsigned short* __restrict__ h16, const float* __restrict__ bias,
    const float* __restrict__ dis, const unsigned int* __restrict__ rowdeg,
    const unsigned int* __restrict__ csr,
    const float* __restrict__ prev, float* __restrict__ out)
{
    const int node = __builtin_amdgcn_readfirstlane(
        (blockIdx.x * blockDim.x + threadIdx.x) >> 6);
    const int lane = threadIdx.x & 63;
    if (node >= NN) return;

    const unsigned int rd = rowdeg[node];
    const int deg = rd & 63;
    const float di = dis[node];

    float a0 = fmaf(di * di, bf2f(h16[(size_t)node * DD + lane]), bias[lane]);
    float a1 = 0.f, a2 = 0.f, a3 = 0.f;

    const unsigned int* seg = csr + (rd >> 6);
    int j = 0;
    for (; j + 3 < deg; j += 4) {
        unsigned int e0 = __builtin_nontemporal_load(seg + j);
        unsigned int e1 = __builtin_nontemporal_load(seg + j + 1);
        unsigned int e2 = __builtin_nontemporal_load(seg + j + 2);
        unsigned int e3 = __builtin_nontemporal_load(seg + j + 3);
        float n0 = bf2f((unsigned short)(e0 & 0x7fffu)) * di;
        float n1 = bf2f((unsigned short)(e1 & 0x7fffu)) * di;
        float n2 = bf2f((unsigned short)(e2 & 0x7fffu)) * di;
        float n3 = bf2f((unsigned short)(e3 & 0x7fffu)) * di;
        a0 = fmaf(n0, bf2f(h16[(size_t)(e0 >> 15) * DD + lane]), a0);
        a1 = fmaf(n1, bf2f(h16[(size_t)(e1 >> 15) * DD + lane]), a1);
        a2 = fmaf(n2, bf2f(h16[(size_t)(e2 >> 15) * DD + lane]), a2);
        a3 = fmaf(n3, bf2f(h16[(size_t)(e3 >> 15) * DD + lane]), a3);
    }
    for (; j < deg; ++j) {
        unsigned int e = __builtin_nontemporal_load(seg + j);
        a0 = fmaf(bf2f((unsigned short)(e & 0x7fffu)) * di,
                  bf2f(h16[(size_t)(e >> 15) * DD + lane]), a0);
    }

    float v = fmaxf((a0 + a1) + (a2 + a3), 0.f);
    int idx = node * DD + lane;
    if (FINAL) {
        float pv = __builtin_nontemporal_load(&prev[idx]);
        __builtin_nontemporal_store(0.5f * (pv + v), &out[idx]);
    } else {
        __builtin_nontemporal_store(v, &out[idx]);
    }
}

__global__ __launch_bounds__(256) void gemm_mfma(
    const float* __restrict__ x, const float* __restrict__ W,
    unsigned short* __restrict__ h16)
{
    __shared__ unsigned short Xs[64 * 72];
    __shared__ unsigned short Ws[64 * 72];
    gemm_body(x, W, h16, blockIdx.x * 64, threadIdx.x, Xs, Ws);
}

// ============= launch =============

extern "C" void kernel_launch(void* const* d_in, const int* in_sizes, int n_in,
                              void* d_out, int out_size, void* d_ws, size_t ws_size,
                              hipStream_t stream) {
    const float* x   = (const float*)d_in[0];
    const int*   ei  = (const int*)d_in[1];
    const float* ewt = (const float*)d_in[2];
    const float* W1  = (const float*)d_in[3];
    const float* b1  = (const float*)d_in[4];
    const float* W2  = (const float*)d_in[5];
    const float* b2  = (const float*)d_in[6];
    float* out = (float*)d_out;

    const int* srcv = ei;
    const int* dstv = ei + NE;

    // workspace layout, 4B slots (d_ws 16B aligned); ~30.5 MB total
    float* wsf = (float*)d_ws;
    int* cursor = (int*)wsf;                                         // @0 (256)
    float* dis = wsf + 256;                                          // 100000 -> pad @100352
    unsigned int* rowdeg = (unsigned int*)(wsf + 100352);            // 100000 -> pad @200448
    unsigned long long* stage = (unsigned long long*)(wsf + 200448); // NBUCK*BCAP u64
    unsigned int* csr = (unsigned int*)(wsf + 200448 + 2 * NBUCK * BCAP);
    unsigned short* h16 = (unsigned short*)(csr + NBUCK * BCAP);     // NN*64 bf16

    const int GB = (NN * 64) / 256;          // 25000 blocks, one wave per node

    hipMemsetAsync(cursor, 0, NBUCK * sizeof(int), stream);
    pass1_gemm<<<NB1 + NB_G, 256, 0, stream>>>(srcv, dstv, ewt, cursor, stage,
                                               x, W1, h16);
    pass2a<<<NBUCK, 512, 0, stream>>>(stage, cursor, rowdeg, dis);
    pass2b<<<NBUCK, 512, 0, stream>>>(stage, cursor, rowdeg, dis, csr);

    gather<false><<<GB, 256, 0, stream>>>(h16, b1, dis, rowdeg, csr, nullptr, out);
    gemm_mfma<<<NB_G, 256, 0, stream>>>(out, W2, h16);
    gather<true><<<GB, 256, 0, stream>>>(h16, b2, dis, rowdeg, csr, out, out);
}